// Round 1
// 637.478 us; speedup vs baseline: 1.0420x; 1.0420x over previous
//
#include <hip/hip_runtime.h>

// Problem constants (fixed by reference file)
#define NROWS   16384
#define HDIM    2048
#define TOPK    4
#define NEXP    64
#define NSLOT   (NROWS * TOPK)        // 65536 expanded slots
#define SLOTS_PER_BLOCK 256
#define NBLK    (NSLOT / SLOTS_PER_BLOCK)  // 256 histogram blocks
#define CHUNK   16                          // hist-blocks per scan chunk
#define NCHUNK  (NBLK / CHUNK)              // 16 chunks

typedef float f4 __attribute__((ext_vector_type(4)));

// ---------------------------------------------------------------------------
// K1: per-block histogram of expert ids (256 slots/block, LDS atomics)
// ---------------------------------------------------------------------------
__global__ void hist_kernel(const int* __restrict__ eidx, int* __restrict__ hist) {
    __shared__ int h[NEXP];
    int t = threadIdx.x;
    if (t < NEXP) h[t] = 0;
    __syncthreads();
    int slot = blockIdx.x * SLOTS_PER_BLOCK + t;
    int e = eidx[slot];
    atomicAdd(&h[e], 1);
    __syncthreads();
    if (t < NEXP) hist[blockIdx.x * NEXP + t] = h[t];
}

// ---------------------------------------------------------------------------
// K2: parallel scan. 1 block x 1024 threads = 16 chunks x 64 experts.
// Serial length per phase drops 256 -> 16 vs the old single-wave version.
//   partial[c][e] = sum of hist over chunk c
//   excl[c][e]    = prefix over chunks  (16-iter LDS loop)
//   expert_off[e] = wave-scan of totals (wave 0)
//   base[b][e]    = expert_off + excl + running within chunk (16-iter loop)
// ---------------------------------------------------------------------------
__global__ void __launch_bounds__(1024) scan_kernel(const int* __restrict__ hist,
                                                    int* __restrict__ base,
                                                    float* __restrict__ out_counts) {
    __shared__ int partial[NCHUNK][NEXP];
    __shared__ int expert_off[NEXP];
    int tid = threadIdx.x;
    int c = tid >> 6;         // chunk 0..15  (one wave per chunk)
    int e = tid & 63;         // expert 0..63 (lane id)
    int b0 = c * CHUNK;

    int s = 0;
    #pragma unroll
    for (int i = 0; i < CHUNK; ++i) s += hist[(b0 + i) * NEXP + e];
    partial[c][e] = s;
    __syncthreads();

    // exclusive prefix over chunks for this (c, e)
    int excl = 0;
    #pragma unroll
    for (int i = 0; i < NCHUNK; ++i) {
        int v = partial[i][e];               // lanes read consecutive banks
        excl += (i < c) ? v : 0;
    }

    // wave 0: expert totals -> counts output + exclusive scan -> expert offsets
    if (tid < 64) {
        int total = 0;
        #pragma unroll
        for (int i = 0; i < NCHUNK; ++i) total += partial[i][tid];
        out_counts[tid] = (float)total;
        int incl = total;
        #pragma unroll
        for (int d = 1; d < 64; d <<= 1) {
            int y = __shfl_up(incl, d, 64);
            if (tid >= d) incl += y;
        }
        expert_off[tid] = incl - total;
    }
    __syncthreads();

    int running = expert_off[e] + excl;
    #pragma unroll
    for (int i = 0; i < CHUNK; ++i) {
        int idx = (b0 + i) * NEXP + e;
        base[idx] = running;
        running += hist[idx];
    }
}

// ---------------------------------------------------------------------------
// K3: stable in-block rank -> destination slot.
//   Writes expanded_row_idx (float), expanded_scale (scattered), dest map (ws).
// ---------------------------------------------------------------------------
__global__ void rank_kernel(const int* __restrict__ eidx, const int* __restrict__ base,
                            const float* __restrict__ scale,
                            int* __restrict__ dest_ws, float* __restrict__ out_idx,
                            float* __restrict__ out_scale) {
    __shared__ int se[SLOTS_PER_BLOCK];
    int t = threadIdx.x;
    int slot = blockIdx.x * SLOTS_PER_BLOCK + t;
    int e = eidx[slot];
    se[t] = e;
    __syncthreads();
    int rank = 0;
    #pragma unroll 8
    for (int i = 0; i < SLOTS_PER_BLOCK; ++i) {
        int v = se[i];
        rank += (i < t && v == e) ? 1 : 0;
    }
    int dest = base[blockIdx.x * NEXP + e] + rank;
    dest_ws[slot] = dest;
    out_idx[slot] = (float)dest;
    out_scale[dest] = scale[slot >> 2];   // slot/TOPK
}

// ---------------------------------------------------------------------------
// K4: token-centric gather. One block per SOURCE token row (16384 blocks).
// Read the 8 KiB row ONCE into registers (2x float4 per lane), then write it
// to the TOPK=4 destination rows. Logical x reads drop 512 MiB -> 128 MiB and
// the 4-way reuse moves from cross-XCD L3 into registers. Nontemporal on both
// sides: x is streamed exactly once, out is never re-read in-kernel.
// ---------------------------------------------------------------------------
__global__ void __launch_bounds__(256) copy_kernel(const f4* __restrict__ x,
                                                   const int* __restrict__ dest_ws,
                                                   f4* __restrict__ out) {
    int row = blockIdx.x;            // source token row
    int t = threadIdx.x;
    const f4* xs = x + (size_t)row * (HDIM / 4);
    f4 v0 = __builtin_nontemporal_load(xs + t);
    f4 v1 = __builtin_nontemporal_load(xs + t + 256);
    const int4 d = *reinterpret_cast<const int4*>(dest_ws + ((size_t)row << 2));
    f4* o0 = out + (size_t)d.x * (HDIM / 4);
    f4* o1 = out + (size_t)d.y * (HDIM / 4);
    f4* o2 = out + (size_t)d.z * (HDIM / 4);
    f4* o3 = out + (size_t)d.w * (HDIM / 4);
    __builtin_nontemporal_store(v0, o0 + t);
    __builtin_nontemporal_store(v1, o0 + t + 256);
    __builtin_nontemporal_store(v0, o1 + t);
    __builtin_nontemporal_store(v1, o1 + t + 256);
    __builtin_nontemporal_store(v0, o2 + t);
    __builtin_nontemporal_store(v1, o2 + t + 256);
    __builtin_nontemporal_store(v0, o3 + t);
    __builtin_nontemporal_store(v1, o3 + t + 256);
}

extern "C" void kernel_launch(void* const* d_in, const int* in_sizes, int n_in,
                              void* d_out, int out_size, void* d_ws, size_t ws_size,
                              hipStream_t stream) {
    const float* x     = (const float*)d_in[0];
    const int*   eidx  = (const int*)d_in[1];
    const float* scale = (const float*)d_in[2];
    // d_in[3] = expert_num (64), compile-time constant here.

    float* out        = (float*)d_out;
    float* out_x      = out;                                   // [65536, 2048]
    float* out_idx    = out + (size_t)NSLOT * HDIM;            // [65536]
    float* out_counts = out_idx + NSLOT;                       // [64]
    float* out_scale  = out_counts + NEXP;                     // [65536]

    int* hist = (int*)d_ws;                 // [NBLK * NEXP]   64 KiB
    int* base = hist + NBLK * NEXP;         // [NBLK * NEXP]   64 KiB
    int* dest = base + NBLK * NEXP;         // [NSLOT]        256 KiB

    hist_kernel<<<NBLK, SLOTS_PER_BLOCK, 0, stream>>>(eidx, hist);
    scan_kernel<<<1, 1024, 0, stream>>>(hist, base, out_counts);
    rank_kernel<<<NBLK, SLOTS_PER_BLOCK, 0, stream>>>(eidx, base, scale,
                                                      dest, out_idx, out_scale);
    copy_kernel<<<NROWS, 256, 0, stream>>>((const f4*)x, dest, (f4*)out_x);
}

// Round 2
// 628.846 us; speedup vs baseline: 1.0563x; 1.0137x over previous
//
#include <hip/hip_runtime.h>

// Problem constants (fixed by reference file)
#define NROWS   16384
#define HDIM    2048
#define TOPK    4
#define NEXP    64
#define NSLOT   (NROWS * TOPK)        // 65536 expanded slots
#define SLOTS_PER_BLOCK 256
#define NBLK    (NSLOT / SLOTS_PER_BLOCK)  // 256 histogram blocks
#define CHUNK   16                          // hist-blocks per scan chunk
#define NCHUNK  (NBLK / CHUNK)              // 16 chunks

typedef float f4 __attribute__((ext_vector_type(4)));

// ---------------------------------------------------------------------------
// K1: fused histogram + stable in-block rank. One pass over eidx.
// Each thread counts matches over the block's 256 eids (LDS broadcast reads):
//   cnt  = total occurrences of its expert in the block
//   rank = occurrences before it (stable rank)
// The rank==0 thread of each expert publishes cnt -> histogram (no atomics).
// packed[slot] = (e << 16) | rank  consumed by the copy kernel.
// ---------------------------------------------------------------------------
__global__ void hist_rank_kernel(const int* __restrict__ eidx,
                                 int* __restrict__ hist,
                                 int* __restrict__ packed) {
    __shared__ int se[SLOTS_PER_BLOCK];
    __shared__ int h[NEXP];
    int t = threadIdx.x;
    if (t < NEXP) h[t] = 0;
    int slot = blockIdx.x * SLOTS_PER_BLOCK + t;
    int e = eidx[slot];
    se[t] = e;
    __syncthreads();
    int rank = 0, cnt = 0;
    #pragma unroll 8
    for (int i = 0; i < SLOTS_PER_BLOCK; ++i) {
        int m = (se[i] == e);                 // wave-uniform LDS addr -> broadcast
        cnt  += m;
        rank += (i < t) ? m : 0;
    }
    packed[slot] = (e << 16) | rank;
    if (rank == 0) h[e] = cnt;                // exactly one writer per (block, e)
    __syncthreads();
    if (t < NEXP) hist[blockIdx.x * NEXP + t] = h[t];
}

// ---------------------------------------------------------------------------
// K2: parallel scan. 1 block x 1024 threads = 16 chunks x 64 experts.
//   partial[c][e] = sum of hist over chunk c
//   excl[c][e]    = prefix over chunks
//   expert_off[e] = wave-scan of totals (wave 0) -> expert_tokens_count out
//   base[b][e]    = expert_off + excl + running within chunk
// ---------------------------------------------------------------------------
__global__ void __launch_bounds__(1024) scan_kernel(const int* __restrict__ hist,
                                                    int* __restrict__ base,
                                                    float* __restrict__ out_counts) {
    __shared__ int partial[NCHUNK][NEXP];
    __shared__ int expert_off[NEXP];
    int tid = threadIdx.x;
    int c = tid >> 6;         // chunk 0..15  (one wave per chunk)
    int e = tid & 63;         // expert 0..63 (lane id)
    int b0 = c * CHUNK;

    int s = 0;
    #pragma unroll
    for (int i = 0; i < CHUNK; ++i) s += hist[(b0 + i) * NEXP + e];
    partial[c][e] = s;
    __syncthreads();

    // exclusive prefix over chunks for this (c, e)
    int excl = 0;
    #pragma unroll
    for (int i = 0; i < NCHUNK; ++i) {
        int v = partial[i][e];
        excl += (i < c) ? v : 0;
    }

    // wave 0: expert totals -> counts output + exclusive scan -> expert offsets
    if (tid < 64) {
        int total = 0;
        #pragma unroll
        for (int i = 0; i < NCHUNK; ++i) total += partial[i][tid];
        out_counts[tid] = (float)total;
        int incl = total;
        #pragma unroll
        for (int d = 1; d < 64; d <<= 1) {
            int y = __shfl_up(incl, d, 64);
            if (tid >= d) incl += y;
        }
        expert_off[tid] = incl - total;
    }
    __syncthreads();

    int running = expert_off[e] + excl;
    #pragma unroll
    for (int i = 0; i < CHUNK; ++i) {
        int idx = (b0 + i) * NEXP + e;
        base[idx] = running;
        running += hist[idx];
    }
}

// ---------------------------------------------------------------------------
// K3: token-centric gather, fused with dest computation + idx/scale outputs.
// One block per SOURCE row. The row's 4 slots (row*4..row*4+3) all fall in
// hist-block row/64, and all their metadata loads are block-uniform -> the
// compiler scalarizes them (s_load), so every thread cheaply knows all 4 dests
// with no LDS / no extra sync. Row data read once into registers, written to
// TOPK=4 destination rows with nontemporal stores (out never re-read here).
// ---------------------------------------------------------------------------
__global__ void __launch_bounds__(256) copy_kernel(const f4* __restrict__ x,
                                                   const int* __restrict__ packed,
                                                   const int* __restrict__ base,
                                                   const float* __restrict__ scale,
                                                   float* __restrict__ out_idx,
                                                   float* __restrict__ out_scale,
                                                   f4* __restrict__ out) {
    int row = blockIdx.x;
    int t = threadIdx.x;
    const f4* xs = x + (size_t)row * (HDIM / 4);
    f4 v0 = __builtin_nontemporal_load(xs + t);
    f4 v1 = __builtin_nontemporal_load(xs + t + 256);

    int slot0 = row << 2;                 // first of the 4 expanded slots
    int b     = row >> 6;                 // hist-block containing all 4 slots
    const int* bb = base + b * NEXP;
    int p0 = packed[slot0 + 0];           // block-uniform loads
    int p1 = packed[slot0 + 1];
    int p2 = packed[slot0 + 2];
    int p3 = packed[slot0 + 3];
    int d0 = bb[p0 >> 16] + (p0 & 0xffff);
    int d1 = bb[p1 >> 16] + (p1 & 0xffff);
    int d2 = bb[p2 >> 16] + (p2 & 0xffff);
    int d3 = bb[p3 >> 16] + (p3 & 0xffff);

    if (t == 0) {
        f4 idx = {(float)d0, (float)d1, (float)d2, (float)d3};
        *reinterpret_cast<f4*>(out_idx + slot0) = idx;   // 16B aligned
        float sc = scale[row];
        out_scale[d0] = sc;
        out_scale[d1] = sc;
        out_scale[d2] = sc;
        out_scale[d3] = sc;
    }

    f4* o0 = out + (size_t)d0 * (HDIM / 4);
    f4* o1 = out + (size_t)d1 * (HDIM / 4);
    f4* o2 = out + (size_t)d2 * (HDIM / 4);
    f4* o3 = out + (size_t)d3 * (HDIM / 4);
    __builtin_nontemporal_store(v0, o0 + t);
    __builtin_nontemporal_store(v1, o0 + t + 256);
    __builtin_nontemporal_store(v0, o1 + t);
    __builtin_nontemporal_store(v1, o1 + t + 256);
    __builtin_nontemporal_store(v0, o2 + t);
    __builtin_nontemporal_store(v1, o2 + t + 256);
    __builtin_nontemporal_store(v0, o3 + t);
    __builtin_nontemporal_store(v1, o3 + t + 256);
}

extern "C" void kernel_launch(void* const* d_in, const int* in_sizes, int n_in,
                              void* d_out, int out_size, void* d_ws, size_t ws_size,
                              hipStream_t stream) {
    const float* x     = (const float*)d_in[0];
    const int*   eidx  = (const int*)d_in[1];
    const float* scale = (const float*)d_in[2];
    // d_in[3] = expert_num (64), compile-time constant here.

    float* out        = (float*)d_out;
    float* out_x      = out;                                   // [65536, 2048]
    float* out_idx    = out + (size_t)NSLOT * HDIM;            // [65536]
    float* out_counts = out_idx + NSLOT;                       // [64]
    float* out_scale  = out_counts + NEXP;                     // [65536]

    int* hist   = (int*)d_ws;                 // [NBLK * NEXP]   64 KiB
    int* base   = hist + NBLK * NEXP;         // [NBLK * NEXP]   64 KiB
    int* packed = base + NBLK * NEXP;         // [NSLOT]        256 KiB

    hist_rank_kernel<<<NBLK, SLOTS_PER_BLOCK, 0, stream>>>(eidx, hist, packed);
    scan_kernel<<<1, 1024, 0, stream>>>(hist, base, out_counts);
    copy_kernel<<<NROWS, 256, 0, stream>>>((const f4*)x, packed, base, scale,
                                           out_idx, out_scale, (f4*)out_x);
}